// Round 2
// baseline (468.441 us; speedup 1.0000x reference)
//
#include <hip/hip_runtime.h>

// out[n,o] = sum_i x[n,i]*W[o,i] + b[o]
// x: 524288x128 fp32, W: 128x128 fp32 (row-major [o][i]), b: 128 fp32, out: 524288x128 fp32
//
// Memory-bound GEMM: 537 MB mandatory HBM traffic -> ~85us floor at 6.3 TB/s.
// fp16 MFMA (16x16x32) with fp32 accumulation; W fragments live entirely in
// registers (loaded once per block from L2), no LDS.

typedef __fp16   fp16x2  __attribute__((ext_vector_type(2)));  // cvt_pkrtz result type
typedef _Float16 half8_t __attribute__((ext_vector_type(8)));  // MFMA A/B operand
typedef float    float4_t __attribute__((ext_vector_type(4)));

constexpr int BATCH = 524288;
constexpr int K = 128;
constexpr int N = 128;
constexpr int ROWS_PER_BLOCK_TILE = 64;                    // 4 waves x 16 rows
constexpr int NUM_TILES = BATCH / ROWS_PER_BLOCK_TILE;     // 8192
constexpr int GRID = 1024;
constexpr int TILES_PER_BLOCK = NUM_TILES / GRID;          // 8

__global__ __launch_bounds__(256, 2)
void linear_mfma_kernel(const float* __restrict__ x,
                        const float* __restrict__ W,
                        const float* __restrict__ bias,
                        float* __restrict__ out)
{
    const int lane = threadIdx.x & 63;
    const int wave = threadIdx.x >> 6;
    const int l15  = lane & 15;   // A: m-row / B: o-col / C: col
    const int quad = lane >> 4;   // A,B: k-subchunk / C: row-quad

    // ---- B fragments (W), held in registers for the whole kernel ----
    // b_frag layout for mfma_f32_16x16x32_f16: lane holds B[k=quad*8+j][o=lane&15]
    //   = W[o=lane&15][k0 + quad*8 + j]  -> 8 contiguous fp32 from W's row.
    half8_t bf[8][4];
#pragma unroll
    for (int t = 0; t < 8; ++t) {
        const float* wp = W + (size_t)(t * 16 + l15) * K + quad * 8;
#pragma unroll
        for (int c = 0; c < 4; ++c) {
            float4_t w0 = *(const float4_t*)(wp + c * 32);
            float4_t w1 = *(const float4_t*)(wp + c * 32 + 4);
            union { half8_t v; fp16x2 h[4]; } u;
            u.h[0] = __builtin_amdgcn_cvt_pkrtz(w0.x, w0.y);
            u.h[1] = __builtin_amdgcn_cvt_pkrtz(w0.z, w0.w);
            u.h[2] = __builtin_amdgcn_cvt_pkrtz(w1.x, w1.y);
            u.h[3] = __builtin_amdgcn_cvt_pkrtz(w1.z, w1.w);
            bf[t][c] = u.v;
        }
    }

    // bias value per lane per o-tile: col = t*16 + l15
    float bv[8];
#pragma unroll
    for (int t = 0; t < 8; ++t) bv[t] = bias[t * 16 + l15];

    // ---- row-tile loop: each block handles TILES_PER_BLOCK contiguous 64-row tiles ----
    for (int it = 0; it < TILES_PER_BLOCK; ++it) {
        const int tile = blockIdx.x * TILES_PER_BLOCK + it;
        const int m0 = tile * ROWS_PER_BLOCK_TILE + wave * 16;

        const float* xp = x + (size_t)(m0 + l15) * K + quad * 8;

        float4_t acc[8];
#pragma unroll
        for (int t = 0; t < 8; ++t) acc[t] = (float4_t)0.0f;

#pragma unroll
        for (int c = 0; c < 4; ++c) {
            float4_t a0 = *(const float4_t*)(xp + c * 32);
            float4_t a1 = *(const float4_t*)(xp + c * 32 + 4);
            union { half8_t v; fp16x2 h[4]; } ua;
            ua.h[0] = __builtin_amdgcn_cvt_pkrtz(a0.x, a0.y);
            ua.h[1] = __builtin_amdgcn_cvt_pkrtz(a0.z, a0.w);
            ua.h[2] = __builtin_amdgcn_cvt_pkrtz(a1.x, a1.y);
            ua.h[3] = __builtin_amdgcn_cvt_pkrtz(a1.z, a1.w);
#pragma unroll
            for (int t = 0; t < 8; ++t)
                acc[t] = __builtin_amdgcn_mfma_f32_16x16x32_f16(ua.v, bf[t][c], acc[t], 0, 0, 0);
        }

        // C/D layout: row = quad*4 + r, col = t*16 + l15
        float* op = out + (size_t)(m0 + quad * 4) * N + l15;
#pragma unroll
        for (int t = 0; t < 8; ++t) {
#pragma unroll
            for (int r = 0; r < 4; ++r) {
                op[(size_t)r * N + t * 16] = acc[t][r] + bv[t];
            }
        }
    }
}

extern "C" void kernel_launch(void* const* d_in, const int* in_sizes, int n_in,
                              void* d_out, int out_size, void* d_ws, size_t ws_size,
                              hipStream_t stream) {
    const float* x = (const float*)d_in[0];
    const float* W = (const float*)d_in[1];
    const float* b = (const float*)d_in[2];
    float* out = (float*)d_out;
    linear_mfma_kernel<<<GRID, 256, 0, stream>>>(x, W, b, out);
}